// Round 8
// baseline (214.479 us; speedup 1.0000x reference)
//
#include <hip/hip_runtime.h>
#include <hip/hip_bf16.h>

// QNet: out[i] = w2 . relu( concat(embed[i], graph_embed[rep[i]]) @ w1^T + b1 ) + b2
// Split: pre = embed @ W1a^T (bf16 MFMA, K=64) + Gb[rep[i]] (fp32, MFMA C-init),
// Gb[b][n] = b1[n] + sum_k graph_embed[b][k] * w1[n][64+k].
//
// SINGLE fused kernel (R5 structure + in-block Gb):
//  - prologue issues the 3 STAGE slots FIRST (fire-and-forget global_load_lds),
//    then computes the block's <=3 Gb rows into LDS under those in-flight loads,
//    then lgkmcnt(0)+s_barrier (no vmcnt(0) drain of the staged slots).
//  - 2 waves/block split the hidden dim (64 each), 4-slot shared LDS ring,
//    k-major pre-swizzled GLOBAL source (LDS dest linear), raw s_barrier +
//    per-wave counted vmcnt, double-buffered LDS dot exchange.
//  - steady-state phases contain NO compiler-tracked global loads (gbv refill
//    is an LDS read; rare span>=3 fallback recomputes per-lane, cold branch).

#define D_LAT 64
#define H_HID 128
#define RING  4
#define TPB   64     // tiles per block

typedef short bf16x8 __attribute__((ext_vector_type(8)));
typedef float f32x4  __attribute__((ext_vector_type(4)));
typedef __attribute__((address_space(3))) float lds_f;

#define MFMA16 __builtin_amdgcn_mfma_f32_16x16x32_bf16

static __device__ inline short f2s(float f) {
    __bf16 h = (__bf16)f;
    return __builtin_bit_cast(short, h);
}
static __device__ inline bf16x8 pack8(f32x4 a, f32x4 b) {
    bf16x8 r;
    r[0] = f2s(a[0]); r[1] = f2s(a[1]); r[2] = f2s(a[2]); r[3] = f2s(a[3]);
    r[4] = f2s(b[0]); r[5] = f2s(b[1]); r[6] = f2s(b[2]); r[7] = f2s(b[3]);
    return r;
}
static __device__ inline void gll16(const float* g, float* l) {
    __builtin_amdgcn_global_load_lds((const __attribute__((address_space(1))) void*)g,
                                     (__attribute__((address_space(3))) void*)l, 16, 0, 0);
}
static __device__ inline void gll4(const int* g, int* l) {
    __builtin_amdgcn_global_load_lds((const __attribute__((address_space(1))) void*)g,
                                     (__attribute__((address_space(3))) void*)l, 4, 0, 0);
}

__global__ __launch_bounds__(128, 4) void qnet_main(
        const float* __restrict__ embed, const int* __restrict__ rep,
        const float* __restrict__ w1, const float* __restrict__ w2,
        const float* __restrict__ b1p, const float* __restrict__ b2,
        const float* __restrict__ ge, float* __restrict__ out) {
    __shared__ float s_emb[RING * 1024];   // 4KB per slot, k-major 16B-unit layout
    __shared__ int   s_rep[RING * 64];
    __shared__ float s_exch[2 * 16];
    __shared__ float s_gb3[3 * H_HID];     // 1.5KB: block's Gb rows

    const int lane = threadIdx.x & 63;
    const int l15  = lane & 15;
    const int g    = lane >> 4;
    const int w    = threadIdx.x >> 6;        // wave role: 0 / 1 (hidden half)
    const int t0   = blockIdx.x * TPB;

    const unsigned emb_base  = (unsigned)(size_t)(lds_f*)s_emb;
    const unsigned rep_base  = (unsigned)(size_t)(lds_f*)(float*)(void*)s_rep;
    const unsigned exch_base = (unsigned)(size_t)(lds_f*)s_exch;

    // k-major pre-swizzled global source: LDS 16B-unit U = j*64+lane holds
    // global unit (row=lane&15, u=j*4+(lane>>4)); src floats = (lane&15)*64 + j*16 + (lane>>4)*4.
#define STAGE_W0(TT, SLOT) do {                                               \
    const float* s0_ = embed + (size_t)(TT) * 1024 + l15 * 64 + g * 4;        \
    float* d_ = s_emb + (SLOT) * 1024;                                        \
    gll16(s0_,      d_);                                                      \
    gll16(s0_ + 16, d_ + 256);                                                \
    gll4(rep + (size_t)(TT) * 16 + l15, s_rep + (SLOT) * 64);                 \
} while (0)
#define STAGE_W1(TT, SLOT) do {                                               \
    const float* s0_ = embed + (size_t)(TT) * 1024 + l15 * 64 + g * 4;        \
    float* d_ = s_emb + (SLOT) * 1024;                                        \
    gll16(s0_ + 32, d_ + 512);                                                \
    gll16(s0_ + 48, d_ + 768);                                                \
} while (0)

    // ---- prologue: staging FIRST, then Gb rows computed under in-flight DMA ----
    if (w == 0) {
        STAGE_W0(t0 + 0, 0); STAGE_W0(t0 + 1, 1); STAGE_W0(t0 + 2, 2);
    } else {
        STAGE_W1(t0 + 0, 0); STAGE_W1(t0 + 1, 1); STAGE_W1(t0 + 2, 2);
    }

    const int bmin = rep[t0 * 16];
    {
        const int span = rep[(t0 + TPB) * 16 - 1] - bmin;
        const int rows = span < 3 ? span + 1 : 3;
        const int h = threadIdx.x;            // 0..127
        const float* wb = w1 + h * (2 * D_LAT) + D_LAT;
        for (int r = 0; r < rows; ++r) {
            const float* ger = ge + (size_t)(bmin + r) * D_LAT;
            float acc = b1p[h];
            #pragma unroll
            for (int kc = 0; kc < 16; ++kc) {
                f32x4 wv = *(const f32x4*)(wb + kc * 4);
                f32x4 gv = *(const f32x4*)(ger + kc * 4);
                acc += wv[0] * gv[0] + wv[1] * gv[1] + wv[2] * gv[2] + wv[3] * gv[3];
            }
            s_gb3[r * H_HID + h] = acc;
        }
    }

    // A fragments: this wave's hidden half. lane holds w1[w*64+nt*16+l15][ks*32+g*8+e]
    bf16x8 wfrag[2][4];
    #pragma unroll
    for (int nt = 0; nt < 4; ++nt) {
        const float* wr = w1 + (w * 64 + nt * 16 + l15) * (2 * D_LAT);
        #pragma unroll
        for (int ks = 0; ks < 2; ++ks) {
            f32x4 lo = *reinterpret_cast<const f32x4*>(wr + ks * 32 + g * 8);
            f32x4 hi = *reinterpret_cast<const f32x4*>(wr + ks * 32 + g * 8 + 4);
            wfrag[ks][nt] = pack8(lo, hi);
        }
    }
    f32x4 w2v[4];
    #pragma unroll
    for (int nt = 0; nt < 4; ++nt)
        w2v[nt] = *reinterpret_cast<const f32x4*>(w2 + w * 64 + nt * 16 + g * 4);
    const float b2v = b2[0];

    // make s_gb3 visible to both waves WITHOUT draining the vm (staging) queue
    asm volatile("s_waitcnt lgkmcnt(0)\n\ts_barrier" ::: "memory");

    int   cur_b = -2;
    f32x4 gbv[4];
    #pragma unroll
    for (int nt = 0; nt < 4; ++nt) gbv[nt] = f32x4{0.f, 0.f, 0.f, 0.f};
    float p_prev = 0.f;

    // gbv refill (LDS rows; cold per-lane recompute for span>=3), MFMA, half dot
#define COMPUTE(P)                                                            \
    int rb0 = __shfl(brow, 0, 64), rb15 = __shfl(brow, 15, 64);               \
    bool uni = (rb0 == rb15);                                                 \
    if (!(uni && rb0 == cur_b)) {                                             \
        const int idx = brow - bmin;                                          \
        if (__builtin_expect(idx >= 3, 0)) {                                  \
            const float* ger_ = ge + (size_t)brow * D_LAT;                    \
            _Pragma("unroll")                                                 \
            for (int nt = 0; nt < 4; ++nt) {                                  \
                _Pragma("unroll")                                             \
                for (int r = 0; r < 4; ++r) {                                 \
                    const int h_ = w * 64 + nt * 16 + g * 4 + r;              \
                    float a_ = b1p[h_];                                       \
                    const float* wb_ = w1 + h_ * (2 * D_LAT) + D_LAT;         \
                    _Pragma("unroll 1")                                       \
                    for (int k = 0; k < D_LAT; ++k) a_ += ger_[k] * wb_[k];   \
                    gbv[nt][r] = a_;                                          \
                }                                                             \
            }                                                                 \
        } else {                                                              \
            const float* sp_ = (const float*)s_gb3 + idx * H_HID + w * 64 + g * 4; \
            gbv[0] = *(const f32x4*)(sp_);      gbv[1] = *(const f32x4*)(sp_ + 16); \
            gbv[2] = *(const f32x4*)(sp_ + 32); gbv[3] = *(const f32x4*)(sp_ + 48); \
        }                                                                     \
        cur_b = uni ? rb0 : -1;                                               \
    }                                                                         \
    bf16x8 a0 = pack8(x0, x1), a1 = pack8(x2, x3);                            \
    float P = 0.f;                                                            \
    _Pragma("unroll")                                                         \
    for (int nt = 0; nt < 4; ++nt) {                                          \
        f32x4 z = gbv[nt];                                                    \
        z = MFMA16(wfrag[0][nt], a0, z, 0, 0, 0);                             \
        z = MFMA16(wfrag[1][nt], a1, z, 0, 0, 0);                             \
        _Pragma("unroll")                                                     \
        for (int r = 0; r < 4; ++r) P += fmaxf(z[r], 0.f) * w2v[nt][r];       \
    }                                                                         \
    P += __shfl_xor(P, 16, 64);                                               \
    P += __shfl_xor(P, 32, 64);

#define PH0(CS, TT, I, WN, DOSTAGE, DOSTORE) do {                             \
    asm volatile("s_waitcnt vmcnt(" #WN ")" ::: "memory");                    \
    __builtin_amdgcn_s_barrier();                                             \
    f32x4 x0, x1, x2, x3; int brow; float xv;                                 \
    {                                                                         \
        unsigned ae = emb_base + (unsigned)(CS) * 4096u + g * 512u + l15 * 16u; \
        unsigned ar = rep_base + (unsigned)(CS) * 256u + l15 * 4u;            \
        unsigned ax = exch_base + (unsigned)(((I) - 1) & 1) * 64u + l15 * 4u; \
        asm volatile(                                                         \
            "ds_read_b128 %0, %6\n\t"                                         \
            "ds_read_b128 %1, %6 offset:256\n\t"                              \
            "ds_read_b128 %2, %6 offset:2048\n\t"                             \
            "ds_read_b128 %3, %6 offset:2304\n\t"                             \
            "ds_read_b32  %4, %7\n\t"                                         \
            "ds_read_b32  %5, %8\n\t"                                         \
            "s_waitcnt lgkmcnt(0)"                                            \
            : "=&v"(x0), "=&v"(x1), "=&v"(x2), "=&v"(x3), "=&v"(brow), "=&v"(xv) \
            : "v"(ae), "v"(ar), "v"(ax) : "memory");                          \
    }                                                                         \
    if (DOSTORE) { if (g == 0) out[((TT) - 1) * 16 + l15] = p_prev + xv + b2v; } \
    if (DOSTAGE) STAGE_W0((TT) + 3, ((CS) + 3) & 3);                          \
    COMPUTE(p)                                                                \
    p_prev = p;                                                               \
} while (0)

#define PH1(CS, TT, I, WN, DOSTAGE) do {                                      \
    asm volatile("s_waitcnt vmcnt(" #WN ") lgkmcnt(0)" ::: "memory");         \
    __builtin_amdgcn_s_barrier();                                             \
    f32x4 x0, x1, x2, x3; int brow;                                           \
    {                                                                         \
        unsigned ae = emb_base + (unsigned)(CS) * 4096u + g * 512u + l15 * 16u; \
        unsigned ar = rep_base + (unsigned)(CS) * 256u + l15 * 4u;            \
        asm volatile(                                                         \
            "ds_read_b128 %0, %5\n\t"                                         \
            "ds_read_b128 %1, %5 offset:256\n\t"                              \
            "ds_read_b128 %2, %5 offset:2048\n\t"                             \
            "ds_read_b128 %3, %5 offset:2304\n\t"                             \
            "ds_read_b32  %4, %6\n\t"                                         \
            "s_waitcnt lgkmcnt(0)"                                            \
            : "=&v"(x0), "=&v"(x1), "=&v"(x2), "=&v"(x3), "=&v"(brow)         \
            : "v"(ae), "v"(ar) : "memory");                                   \
    }                                                                         \
    if (DOSTAGE) STAGE_W1((TT) + 3, ((CS) + 3) & 3);                          \
    COMPUTE(p)                                                                \
    {                                                                         \
        unsigned ax = exch_base + (unsigned)((I) & 1) * 64u + l15 * 4u;       \
        if (g == 0)                                                           \
            asm volatile("ds_write_b32 %0, %1" :: "v"(ax), "v"(p) : "memory"); \
    }                                                                         \
} while (0)

    if (w == 0) {
        PH0(0, t0 + 0, 0, 6, true, false);
        PH0(1, t0 + 1, 1, 6, true, true);
        PH0(2, t0 + 2, 2, 7, true, true);
        for (int i = 3; i <= 60; ++i)
            PH0((i & 3), t0 + i, i, 8, true, true);
        PH0(1, t0 + 61, 61, 8, false, true);
        PH0(2, t0 + 62, 62, 5, false, true);
        PH0(3, t0 + 63, 63, 2, false, true);
        // final combine for tile t0+63
        __builtin_amdgcn_s_barrier();
        float xv;
        unsigned ax = exch_base + (unsigned)(63 & 1) * 64u + l15 * 4u;
        asm volatile("ds_read_b32 %0, %1\n\ts_waitcnt lgkmcnt(0)"
                     : "=v"(xv) : "v"(ax) : "memory");
        if (g == 0) out[(t0 + 63) * 16 + l15] = p_prev + xv + b2v;
    } else {
        PH1(0, t0 + 0, 0, 4, true);
        PH1(1, t0 + 1, 1, 4, true);
        PH1(2, t0 + 2, 2, 4, true);
        for (int i = 3; i <= 60; ++i)
            PH1((i & 3), t0 + i, i, 4, true);
        PH1(1, t0 + 61, 61, 4, false);
        PH1(2, t0 + 62, 62, 2, false);
        PH1(3, t0 + 63, 63, 0, false);
        asm volatile("s_waitcnt lgkmcnt(0)" ::: "memory");
        __builtin_amdgcn_s_barrier();
    }

#undef PH0
#undef PH1
#undef COMPUTE
#undef STAGE_W0
#undef STAGE_W1
}

extern "C" void kernel_launch(void* const* d_in, const int* in_sizes, int n_in,
                              void* d_out, int out_size, void* d_ws, size_t ws_size,
                              hipStream_t stream) {
    const float* embed = (const float*)d_in[0];
    const float* ge    = (const float*)d_in[1];
    const int*   rep   = (const int*)d_in[2];
    const float* w1    = (const float*)d_in[3];
    const float* b1    = (const float*)d_in[4];
    const float* w2    = (const float*)d_in[5];
    const float* b2    = (const float*)d_in[6];
    float* out = (float*)d_out;
    (void)d_ws; (void)ws_size; (void)out_size; (void)n_in;

    const int N = in_sizes[0] / D_LAT;
    const int num_tiles = N / 16;

    // single dispatch: 2048 blocks x 128 thr, ~18.7KB LDS -> 8 blocks/CU
    qnet_main<<<num_tiles / TPB, 128, 0, stream>>>(embed, rep, w1, w2, b1, b2, ge, out);
}

// Round 9
// 186.408 us; speedup vs baseline: 1.1506x; 1.1506x over previous
//
#include <hip/hip_runtime.h>
#include <hip/hip_bf16.h>

// QNet: out[i] = w2 . relu( concat(embed[i], graph_embed[rep[i]]) @ w1^T + b1 ) + b2
// Split: pre = embed @ W1a^T (bf16 MFMA, K=64) + Gb[rep[i]] (fp32, MFMA C-init),
// Gb[b][n] = b1[n] + sum_k graph_embed[b][k] * w1[n][64+k]  (separate tiny kernel).
//
// Register-staged pipeline (no LDS): 2048 waves, contiguous 64-tile chunks,
// 4-deep hand-unrolled slot ring in VGPRs (~16KB in flight per wave via the
// regular load/MSHR path instead of the global_load_lds DMA queue).
// gb row register-cached via cur_b (changes <=2x per wave on sorted rep) ->
// steady-state phases have no extra compiler-tracked loads to force drains.

#define D_LAT 64
#define H_HID 128

typedef short bf16x8 __attribute__((ext_vector_type(8)));
typedef float f32x4  __attribute__((ext_vector_type(4)));

#define MFMA16 __builtin_amdgcn_mfma_f32_16x16x32_bf16

static __device__ inline short f2s(float f) {
    __bf16 h = (__bf16)f;               // pairs fuse to v_cvt_pk_bf16_f32
    return __builtin_bit_cast(short, h);
}
static __device__ inline bf16x8 pack8(f32x4 a, f32x4 b) {
    bf16x8 r;
    r[0] = f2s(a[0]); r[1] = f2s(a[1]); r[2] = f2s(a[2]); r[3] = f2s(a[3]);
    r[4] = f2s(b[0]); r[5] = f2s(b[1]); r[6] = f2s(b[2]); r[7] = f2s(b[3]);
    return r;
}

// Gb[b][n] = b1[n] + sum_{k<64} graph_embed[b][k] * w1[n][64+k]
__global__ void gb_kernel(const float* __restrict__ ge, const float* __restrict__ w1,
                          const float* __restrict__ b1, float* __restrict__ gb) {
    __shared__ float s[D_LAT];
    const int b = blockIdx.x, n = threadIdx.x;
    if (threadIdx.x < D_LAT) s[threadIdx.x] = ge[b * D_LAT + threadIdx.x];
    __syncthreads();
    float acc = b1[n];
    const float* wr = w1 + n * (2 * D_LAT) + D_LAT;
    #pragma unroll
    for (int k = 0; k < D_LAT; ++k) acc += s[k] * wr[k];
    gb[b * H_HID + n] = acc;
}

struct Tile { f32x4 f0, f1, f2, f3; int b; };

static __device__ inline Tile load_tile(const float* __restrict__ embed,
                                        const int* __restrict__ rep,
                                        int t, int l15, int g) {
    Tile r;
    // lane reads row l15 of the tile, k-chunk g*8 (32B contiguous), then +32 floats
    const float* ap = embed + (size_t)(t * 16 + l15) * D_LAT + g * 8;
    r.f0 = *reinterpret_cast<const f32x4*>(ap);
    r.f1 = *reinterpret_cast<const f32x4*>(ap + 4);
    r.f2 = *reinterpret_cast<const f32x4*>(ap + 32);
    r.f3 = *reinterpret_cast<const f32x4*>(ap + 36);
    r.b  = rep[t * 16 + l15];
    return r;
}

__global__ __launch_bounds__(256, 2) void qnet_main(
        const float* __restrict__ embed, const int* __restrict__ rep,
        const float* __restrict__ w1, const float* __restrict__ w2,
        const float* __restrict__ b2, const float* __restrict__ gb,
        float* __restrict__ out, int num_tiles) {
    const int lane = threadIdx.x & 63;
    const int l15  = lane & 15;
    const int g    = lane >> 4;
    const int wid  = (blockIdx.x * blockDim.x + threadIdx.x) >> 6;
    const int nw   = (gridDim.x * blockDim.x) >> 6;

    // A fragments (W1a): lane holds w1[nt*16+l15][ks*32 + g*8 + e]
    bf16x8 wfrag[2][8];
    #pragma unroll
    for (int nt = 0; nt < 8; ++nt) {
        const float* wr = w1 + (nt * 16 + l15) * (2 * D_LAT);
        #pragma unroll
        for (int ks = 0; ks < 2; ++ks) {
            f32x4 lo = *reinterpret_cast<const f32x4*>(wr + ks * 32 + g * 8);
            f32x4 hi = *reinterpret_cast<const f32x4*>(wr + ks * 32 + g * 8 + 4);
            wfrag[ks][nt] = pack8(lo, hi);
        }
    }
    // epilogue w2 vector: lane's hidden indices nt*16 + g*4 + r
    f32x4 w2v[8];
    #pragma unroll
    for (int nt = 0; nt < 8; ++nt)
        w2v[nt] = *reinterpret_cast<const f32x4*>(w2 + nt * 16 + g * 4);
    const float b2v = b2[0];

    const int tpw = num_tiles / nw;          // 64
    const int t0  = wid * tpw;
    const int t1  = t0 + tpw;

    int   cur_b = -2;
    f32x4 gbv[8];
    #pragma unroll
    for (int nt = 0; nt < 8; ++nt) gbv[nt] = f32x4{0.f, 0.f, 0.f, 0.f};

    // consume slot S (tile TT), refill S with tile TT+4, MFMA w/ gb C-init, dot
#define STEP(S, TT) do {                                                      \
    bf16x8 a0 = pack8(S.f0, S.f1);                                            \
    bf16x8 a1 = pack8(S.f2, S.f3);                                            \
    const int brow = S.b;                                                     \
    const int tn = (TT) + 4;                                                  \
    if (tn < t1) S = load_tile(embed, rep, tn, l15, g);                       \
    const int rb0 = __shfl(brow, 0, 64), rb15 = __shfl(brow, 15, 64);         \
    const bool uni = (rb0 == rb15);                                           \
    if (!(uni && rb0 == cur_b)) {                                             \
        const float* gp = gb + (size_t)brow * H_HID + g * 4;                  \
        _Pragma("unroll")                                                     \
        for (int nt = 0; nt < 8; ++nt)                                        \
            gbv[nt] = *reinterpret_cast<const f32x4*>(gp + nt * 16);          \
        cur_b = uni ? rb0 : -1;                                               \
    }                                                                         \
    float p = 0.f;                                                            \
    _Pragma("unroll")                                                         \
    for (int nt = 0; nt < 8; ++nt) {                                          \
        f32x4 z = gbv[nt];                                                    \
        z = MFMA16(wfrag[0][nt], a0, z, 0, 0, 0);                             \
        z = MFMA16(wfrag[1][nt], a1, z, 0, 0, 0);                             \
        _Pragma("unroll")                                                     \
        for (int r = 0; r < 4; ++r) p += fmaxf(z[r], 0.f) * w2v[nt][r];       \
    }                                                                         \
    p += __shfl_xor(p, 16, 64);                                               \
    p += __shfl_xor(p, 32, 64);                                               \
    if (g == 0) out[(TT) * 16 + l15] = p + b2v;                               \
} while (0)

    // prologue: 4 slots in flight (~16KB/wave)
    Tile A = load_tile(embed, rep, t0 + 0, l15, g);
    Tile B = load_tile(embed, rep, t0 + 1, l15, g);
    Tile C = load_tile(embed, rep, t0 + 2, l15, g);
    Tile D = load_tile(embed, rep, t0 + 3, l15, g);

    for (int i = t0; i < t1; i += 4) {       // tpw divisible by 4
        STEP(A, i + 0);
        STEP(B, i + 1);
        STEP(C, i + 2);
        STEP(D, i + 3);
    }
#undef STEP
}

extern "C" void kernel_launch(void* const* d_in, const int* in_sizes, int n_in,
                              void* d_out, int out_size, void* d_ws, size_t ws_size,
                              hipStream_t stream) {
    const float* embed = (const float*)d_in[0];
    const float* ge    = (const float*)d_in[1];
    const int*   rep   = (const int*)d_in[2];
    const float* w1    = (const float*)d_in[3];
    const float* b1    = (const float*)d_in[4];
    const float* w2    = (const float*)d_in[5];
    const float* b2    = (const float*)d_in[6];
    float* out = (float*)d_out;
    float* gb  = (float*)d_ws;                       // 512*128*4 = 256 KB

    const int N  = in_sizes[0] / D_LAT;
    const int Bg = in_sizes[1] / D_LAT;
    const int num_tiles = N / 16;

    gb_kernel<<<Bg, H_HID, 0, stream>>>(ge, w1, b1, gb);
    // 512 blocks x 256 thr = 2048 waves, contiguous 64-tile chunks, no LDS
    qnet_main<<<512, 256, 0, stream>>>(embed, rep, w1, w2, b2, gb, out, num_tiles);
}

// Round 10
// 125.525 us; speedup vs baseline: 1.7087x; 1.4850x over previous
//
#include <hip/hip_runtime.h>
#include <hip/hip_bf16.h>

// QNet: out[i] = w2 . relu( concat(embed[i], graph_embed[rep[i]]) @ w1^T + b1 ) + b2
// Split: pre = embed @ W1a^T (bf16 MFMA, K=64) + Gb[rep[i]] (fp32, MFMA C-init),
// Gb[b][n] = b1[n] + sum_k graph_embed[b][k] * w1[n][64+k].
//
// Structure (session best, R5): 2048 blocks x 2 waves. Waves split the hidden
// dim (64 each): wfrag/w2v/gbv/acc halve -> 16 waves/CU. Shared 4-slot LDS ring
// staged via global_load_lds with k-major pre-swizzled GLOBAL source (LDS dest
// stays DMA-linear) so ds_read_b128 is bank-balanced. Raw s_barrier + per-wave
// counted vmcnt (never __syncthreads mid-pipeline -> no vmcnt(0) drain).
// Partial dots combined via double-buffered LDS exchange, pipelined one phase.
// Separate tiny gb_kernel (both fusion orderings measured slower: R6/R8).

#define D_LAT 64
#define H_HID 128
#define RING  4
#define TPB   64     // tiles per block

typedef short bf16x8 __attribute__((ext_vector_type(8)));
typedef float f32x4  __attribute__((ext_vector_type(4)));
typedef __attribute__((address_space(3))) float lds_f;

#define MFMA16 __builtin_amdgcn_mfma_f32_16x16x32_bf16

static __device__ inline short f2s(float f) {
    __bf16 h = (__bf16)f;
    return __builtin_bit_cast(short, h);
}
static __device__ inline bf16x8 pack8(f32x4 a, f32x4 b) {
    bf16x8 r;
    r[0] = f2s(a[0]); r[1] = f2s(a[1]); r[2] = f2s(a[2]); r[3] = f2s(a[3]);
    r[4] = f2s(b[0]); r[5] = f2s(b[1]); r[6] = f2s(b[2]); r[7] = f2s(b[3]);
    return r;
}
static __device__ inline void gll16(const float* g, float* l) {
    __builtin_amdgcn_global_load_lds((const __attribute__((address_space(1))) void*)g,
                                     (__attribute__((address_space(3))) void*)l, 16, 0, 0);
}
static __device__ inline void gll4(const int* g, int* l) {
    __builtin_amdgcn_global_load_lds((const __attribute__((address_space(1))) void*)g,
                                     (__attribute__((address_space(3))) void*)l, 4, 0, 0);
}

// Gb[b][n] = b1[n] + sum_{k<64} graph_embed[b][k] * w1[n][64+k]
__global__ void gb_kernel(const float* __restrict__ ge, const float* __restrict__ w1,
                          const float* __restrict__ b1, float* __restrict__ gb) {
    __shared__ float s[D_LAT];
    const int b = blockIdx.x, n = threadIdx.x;
    if (threadIdx.x < D_LAT) s[threadIdx.x] = ge[b * D_LAT + threadIdx.x];
    __syncthreads();
    float acc = b1[n];
    const float* wr = w1 + n * (2 * D_LAT) + D_LAT;
    #pragma unroll
    for (int k = 0; k < D_LAT; ++k) acc += s[k] * wr[k];
    gb[b * H_HID + n] = acc;
}

__global__ __launch_bounds__(128, 4) void qnet_main(
        const float* __restrict__ embed, const int* __restrict__ rep,
        const float* __restrict__ w1, const float* __restrict__ w2,
        const float* __restrict__ b2, const float* __restrict__ gb,
        float* __restrict__ out) {
    __shared__ float s_emb[RING * 1024];   // 4KB per slot, k-major 16B-unit layout
    __shared__ int   s_rep[RING * 64];
    __shared__ float s_exch[2 * 16];

    const int lane = threadIdx.x & 63;
    const int l15  = lane & 15;
    const int g    = lane >> 4;
    const int w    = threadIdx.x >> 6;        // wave role: 0 / 1 (hidden half)
    const int t0   = blockIdx.x * TPB;

    // A fragments: this wave's hidden half. lane holds w1[w*64+nt*16+l15][ks*32+g*8+e]
    bf16x8 wfrag[2][4];
    #pragma unroll
    for (int nt = 0; nt < 4; ++nt) {
        const float* wr = w1 + (w * 64 + nt * 16 + l15) * (2 * D_LAT);
        #pragma unroll
        for (int ks = 0; ks < 2; ++ks) {
            f32x4 lo = *reinterpret_cast<const f32x4*>(wr + ks * 32 + g * 8);
            f32x4 hi = *reinterpret_cast<const f32x4*>(wr + ks * 32 + g * 8 + 4);
            wfrag[ks][nt] = pack8(lo, hi);
        }
    }
    f32x4 w2v[4];
    #pragma unroll
    for (int nt = 0; nt < 4; ++nt)
        w2v[nt] = *reinterpret_cast<const f32x4*>(w2 + w * 64 + nt * 16 + g * 4);
    const float b2v = b2[0];

    const unsigned emb_base  = (unsigned)(size_t)(lds_f*)s_emb;
    const unsigned rep_base  = (unsigned)(size_t)(lds_f*)(float*)(void*)s_rep;
    const unsigned exch_base = (unsigned)(size_t)(lds_f*)s_exch;

    int   cur_b = -2;
    f32x4 gbv[4];
    #pragma unroll
    for (int nt = 0; nt < 4; ++nt) gbv[nt] = f32x4{0.f, 0.f, 0.f, 0.f};
    float p_prev = 0.f;

    // k-major pre-swizzled global source: LDS 16B-unit U = j*64+lane holds
    // global unit (row=lane&15, u=j*4+(lane>>4)); src floats = (lane&15)*64 + j*16 + (lane>>4)*4.
#define STAGE_W0(TT, SLOT) do {                                               \
    const float* s0_ = embed + (size_t)(TT) * 1024 + l15 * 64 + g * 4;        \
    float* d_ = s_emb + (SLOT) * 1024;                                        \
    gll16(s0_,      d_);                                                      \
    gll16(s0_ + 16, d_ + 256);                                                \
    gll4(rep + (size_t)(TT) * 16 + l15, s_rep + (SLOT) * 64);                 \
} while (0)
#define STAGE_W1(TT, SLOT) do {                                               \
    const float* s0_ = embed + (size_t)(TT) * 1024 + l15 * 64 + g * 4;        \
    float* d_ = s_emb + (SLOT) * 1024;                                        \
    gll16(s0_ + 32, d_ + 512);                                                \
    gll16(s0_ + 48, d_ + 768);                                                \
} while (0)

    // shared compute tail: refill gbv on graph change, MFMA (C-init = gbv), dot half
#define COMPUTE(P)                                                            \
    int rb0 = __shfl(brow, 0, 64), rb15 = __shfl(brow, 15, 64);               \
    bool uni = (rb0 == rb15);                                                 \
    if (!(uni && rb0 == cur_b)) {                                             \
        const float* gp = gb + (size_t)brow * H_HID + w * 64 + g * 4;         \
        gbv[0] = *(const f32x4*)(gp);                                         \
        gbv[1] = *(const f32x4*)(gp + 16);                                    \
        gbv[2] = *(const f32x4*)(gp + 32);                                    \
        gbv[3] = *(const f32x4*)(gp + 48);                                    \
        cur_b = uni ? rb0 : -1;                                               \
    }                                                                         \
    bf16x8 a0 = pack8(x0, x1), a1 = pack8(x2, x3);                            \
    float P = 0.f;                                                            \
    _Pragma("unroll")                                                         \
    for (int nt = 0; nt < 4; ++nt) {                                          \
        f32x4 z = gbv[nt];                                                    \
        z = MFMA16(wfrag[0][nt], a0, z, 0, 0, 0);                             \
        z = MFMA16(wfrag[1][nt], a1, z, 0, 0, 0);                             \
        _Pragma("unroll")                                                     \
        for (int r = 0; r < 4; ++r) P += fmaxf(z[r], 0.f) * w2v[nt][r];       \
    }                                                                         \
    P += __shfl_xor(P, 16, 64);                                               \
    P += __shfl_xor(P, 32, 64);

#define PH0(CS, TT, I, WN, DOSTAGE, DOSTORE) do {                             \
    asm volatile("s_waitcnt vmcnt(" #WN ")" ::: "memory");                    \
    __builtin_amdgcn_s_barrier();                                             \
    f32x4 x0, x1, x2, x3; int brow; float xv;                                 \
    {                                                                         \
        unsigned ae = emb_base + (unsigned)(CS) * 4096u + g * 512u + l15 * 16u; \
        unsigned ar = rep_base + (unsigned)(CS) * 256u + l15 * 4u;            \
        unsigned ax = exch_base + (unsigned)(((I) - 1) & 1) * 64u + l15 * 4u; \
        asm volatile(                                                         \
            "ds_read_b128 %0, %6\n\t"                                         \
            "ds_read_b128 %1, %6 offset:256\n\t"                              \
            "ds_read_b128 %2, %6 offset:2048\n\t"                             \
            "ds_read_b128 %3, %6 offset:2304\n\t"                             \
            "ds_read_b32  %4, %7\n\t"                                         \
            "ds_read_b32  %5, %8\n\t"                                         \
            "s_waitcnt lgkmcnt(0)"                                            \
            : "=&v"(x0), "=&v"(x1), "=&v"(x2), "=&v"(x3), "=&v"(brow), "=&v"(xv) \
            : "v"(ae), "v"(ar), "v"(ax) : "memory");                          \
    }                                                                         \
    if (DOSTORE) { if (g == 0) out[((TT) - 1) * 16 + l15] = p_prev + xv + b2v; } \
    if (DOSTAGE) STAGE_W0((TT) + 3, ((CS) + 3) & 3);                          \
    COMPUTE(p)                                                                \
    p_prev = p;                                                               \
} while (0)

#define PH1(CS, TT, I, WN, DOSTAGE) do {                                      \
    asm volatile("s_waitcnt vmcnt(" #WN ") lgkmcnt(0)" ::: "memory");         \
    __builtin_amdgcn_s_barrier();                                             \
    f32x4 x0, x1, x2, x3; int brow;                                           \
    {                                                                         \
        unsigned ae = emb_base + (unsigned)(CS) * 4096u + g * 512u + l15 * 16u; \
        unsigned ar = rep_base + (unsigned)(CS) * 256u + l15 * 4u;            \
        asm volatile(                                                         \
            "ds_read_b128 %0, %5\n\t"                                         \
            "ds_read_b128 %1, %5 offset:256\n\t"                              \
            "ds_read_b128 %2, %5 offset:2048\n\t"                             \
            "ds_read_b128 %3, %5 offset:2304\n\t"                             \
            "ds_read_b32  %4, %6\n\t"                                         \
            "s_waitcnt lgkmcnt(0)"                                            \
            : "=&v"(x0), "=&v"(x1), "=&v"(x2), "=&v"(x3), "=&v"(brow)         \
            : "v"(ae), "v"(ar) : "memory");                                   \
    }                                                                         \
    if (DOSTAGE) STAGE_W1((TT) + 3, ((CS) + 3) & 3);                          \
    COMPUTE(p)                                                                \
    {                                                                         \
        unsigned ax = exch_base + (unsigned)((I) & 1) * 64u + l15 * 4u;       \
        if (g == 0)                                                           \
            asm volatile("ds_write_b32 %0, %1" :: "v"(ax), "v"(p) : "memory"); \
    }                                                                         \
} while (0)

    if (w == 0) {
        STAGE_W0(t0 + 0, 0);
        STAGE_W0(t0 + 1, 1);
        STAGE_W0(t0 + 2, 2);
        PH0(0, t0 + 0, 0, 6, true, false);
        PH0(1, t0 + 1, 1, 6, true, true);
        PH0(2, t0 + 2, 2, 7, true, true);
        for (int i = 3; i <= 60; ++i)
            PH0((i & 3), t0 + i, i, 8, true, true);
        PH0(1, t0 + 61, 61, 8, false, true);
        PH0(2, t0 + 62, 62, 5, false, true);
        PH0(3, t0 + 63, 63, 2, false, true);
        // final combine for tile t0+63
        __builtin_amdgcn_s_barrier();
        float xv;
        unsigned ax = exch_base + (unsigned)(63 & 1) * 64u + l15 * 4u;
        asm volatile("ds_read_b32 %0, %1\n\ts_waitcnt lgkmcnt(0)"
                     : "=v"(xv) : "v"(ax) : "memory");
        if (g == 0) out[(t0 + 63) * 16 + l15] = p_prev + xv + b2v;
    } else {
        STAGE_W1(t0 + 0, 0);
        STAGE_W1(t0 + 1, 1);
        STAGE_W1(t0 + 2, 2);
        PH1(0, t0 + 0, 0, 4, true);
        PH1(1, t0 + 1, 1, 4, true);
        PH1(2, t0 + 2, 2, 4, true);
        for (int i = 3; i <= 60; ++i)
            PH1((i & 3), t0 + i, i, 4, true);
        PH1(1, t0 + 61, 61, 4, false);
        PH1(2, t0 + 62, 62, 2, false);
        PH1(3, t0 + 63, 63, 0, false);
        asm volatile("s_waitcnt lgkmcnt(0)" ::: "memory");
        __builtin_amdgcn_s_barrier();
    }

#undef PH0
#undef PH1
#undef COMPUTE
#undef STAGE_W0
#undef STAGE_W1
}

extern "C" void kernel_launch(void* const* d_in, const int* in_sizes, int n_in,
                              void* d_out, int out_size, void* d_ws, size_t ws_size,
                              hipStream_t stream) {
    const float* embed = (const float*)d_in[0];
    const float* ge    = (const float*)d_in[1];
    const int*   rep   = (const int*)d_in[2];
    const float* w1    = (const float*)d_in[3];
    const float* b1    = (const float*)d_in[4];
    const float* w2    = (const float*)d_in[5];
    const float* b2    = (const float*)d_in[6];
    float* out = (float*)d_out;
    float* gb  = (float*)d_ws;                       // 512*128*4 = 256 KB

    const int N = in_sizes[0] / D_LAT;
    const int B = in_sizes[1] / D_LAT;
    const int num_tiles = N / 16;

    gb_kernel<<<B, H_HID, 0, stream>>>(ge, w1, b1, gb);
    // 2048 blocks x 128 thr (2 waves, hidden-split); 17.2KB LDS -> 8 blocks/CU
    qnet_main<<<num_tiles / TPB, 128, 0, stream>>>(embed, rep, w1, w2, b2, gb, out);
}